// Round 1
// baseline (570.352 us; speedup 1.0000x reference)
//
#include <hip/hip_runtime.h>
#include <stdint.h>

// Problem constants
// B=8, CIN=128, COUT=256, H=256, W=256 -> pooled 128x128, out (8,256,128,128) fp32

// ---------------------------------------------------------------------------
// Kernel 0: weight prep. One block per output channel (256 blocks, 128 thr).
// Produces: packedW[oc][9][4] (bit c%32 of word c/32 = sign(w)>0),
//           scaleW[oc] = mean |w| over 1152, popcW[oc][9] = popcount of tap.
// ---------------------------------------------------------------------------
__global__ __launch_bounds__(128) void wprep_kernel(const float* __restrict__ w,
                                                    uint32_t* __restrict__ packedW,
                                                    float* __restrict__ scaleW,
                                                    int* __restrict__ popcW) {
    int oc = blockIdx.x;
    int cin = threadIdx.x;              // 0..127
    const float* wp = w + ((long)oc * 128 + cin) * 9;
    float wk[9];
    float sabs = 0.f;
#pragma unroll
    for (int k = 0; k < 9; ++k) { wk[k] = wp[k]; sabs += fabsf(wk[k]); }
    int gi = cin >> 6;                  // wave id 0/1
    int lane = cin & 63;
    __shared__ float ssum[2];
    __shared__ int spc[2][9];
    // wave-reduce |w| sum
    for (int off = 32; off > 0; off >>= 1) sabs += __shfl_down(sabs, off, 64);
    if (lane == 0) ssum[gi] = sabs;
#pragma unroll
    for (int k = 0; k < 9; ++k) {
        unsigned long long m = __ballot(wk[k] > 0.f);
        if (lane == 0) {
            packedW[(oc * 9 + k) * 4 + 2 * gi]     = (uint32_t)m;
            packedW[(oc * 9 + k) * 4 + 2 * gi + 1] = (uint32_t)(m >> 32);
            spc[gi][k] = __popcll(m);
        }
    }
    __syncthreads();
    if (cin == 0) scaleW[oc] = (ssum[0] + ssum[1]) * (1.0f / 1152.0f);
    if (cin < 9) popcW[oc * 9 + cin] = spc[0][cin] + spc[1][cin];
}

// ---------------------------------------------------------------------------
// Kernel 1: avgpool 2x2 + bias + sign -> channel-bit-packed activations.
// Grid (128 h, 8 b), 256 threads. packedA[b][h][w][4] u32, bit i of word q =
// (pooled[c=32q+i] + bias > 0).
// ---------------------------------------------------------------------------
__global__ __launch_bounds__(256) void pool_pack_kernel(const float* __restrict__ x,
                                                        const float* __restrict__ bias,
                                                        uint32_t* __restrict__ packedA) {
    int h = blockIdx.x;    // pooled row 0..127
    int b = blockIdx.y;    // 0..7
    int tid = threadIdx.x;
    __shared__ float sbias[128];
    __shared__ uint8_t sb[128 * 132];   // [c][w] bytes, row stride 132
    if (tid < 128) sbias[tid] = bias[tid];
    __syncthreads();
    const float4* x4 = reinterpret_cast<const float4*>(x);
    // channel row pitch in float4: 64 (W=256); channel pitch: 256*64
#pragma unroll 4
    for (int it = 0; it < 32; ++it) {
        int j = it * 256 + tid;         // [0, 8192)
        int c = j >> 6;                 // 0..127
        int wq = j & 63;                // float4 col -> output pixels 2wq, 2wq+1
        long base = ((long)(b * 128 + c) * 256 + 2 * h) * 64 + wq;
        float4 f0 = x4[base];
        float4 f1 = x4[base + 64];
        float p0 = (f0.x + f0.y + f1.x + f1.y) * 0.25f + sbias[c];
        float p1 = (f0.z + f0.w + f1.z + f1.w) * 0.25f + sbias[c];
        uint16_t v = (uint16_t)((p0 > 0.f ? 1u : 0u) | ((p1 > 0.f ? 1u : 0u) << 8));
        *reinterpret_cast<uint16_t*>(&sb[c * 132 + 2 * wq]) = v;
    }
    __syncthreads();
    // transpose bytes -> packed words; lanes: q fast => coalesced u32 stores
#pragma unroll
    for (int it = 0; it < 2; ++it) {
        int idx = it * 256 + tid;       // [0,512)
        int q = idx & 3;
        int w = idx >> 2;
        uint32_t word = 0;
#pragma unroll
        for (int i = 0; i < 32; ++i)
            word |= ((uint32_t)sb[(32 * q + i) * 132 + w]) << i;
        packedA[(((long)b * 128 + h) * 128 + w) * 4 + q] = word;
    }
}

// ---------------------------------------------------------------------------
// Kernel 2: XNOR-popcount 3x3 conv + RPReLU epilogue.
// Grid (128 h, 8 b), 256 threads = 4 waves. Wave wv handles oc in
// [64*wv, 64*wv+64); lane handles pixels w=lane and w=lane+64.
// Activation frags (9 taps x 2 px) live in registers across the oc loop.
// Zero-padded halo; border taps fixed via popcW correction.
// ---------------------------------------------------------------------------
__global__ __launch_bounds__(256, 3) void conv_kernel(const uint32_t* __restrict__ packedA,
                                                      const uint32_t* __restrict__ packedW,
                                                      const float* __restrict__ scaleW,
                                                      const int* __restrict__ popcW,
                                                      const float* __restrict__ pb0,
                                                      const float* __restrict__ alpha,
                                                      const float* __restrict__ pb1,
                                                      float* __restrict__ out) {
    int h = blockIdx.x;
    int b = blockIdx.y;
    int tid = threadIdx.x;
    __shared__ uint32_t wlds[256 * 36];   // 36 KB: [oc][tap][word]
    __shared__ uint4 alds[3][130];        // 3 halo rows, 1-px zero pad each side
    for (int i = tid; i < 256 * 36; i += 256) wlds[i] = packedW[i];
    for (int i = tid; i < 3 * 130; i += 256) {
        int r = i / 130, col = i % 130;
        int hh = h - 1 + r;
        uint4 v = make_uint4(0u, 0u, 0u, 0u);
        if (col >= 1 && col <= 128 && hh >= 0 && hh < 128) {
            const uint4* pa = reinterpret_cast<const uint4*>(packedA);
            v = pa[((long)b * 128 + hh) * 128 + (col - 1)];
        }
        alds[r][col] = v;
    }
    __syncthreads();

    int wv = tid >> 6;
    int lane = tid & 63;
    int px0 = lane;        // 0..63
    int px1 = lane + 64;   // 64..127

    uint4 a0[9], a1[9];
#pragma unroll
    for (int r = 0; r < 3; ++r)
#pragma unroll
        for (int dx = 0; dx < 3; ++dx) {
            a0[r * 3 + dx] = alds[r][px0 + dx];
            a1[r * 3 + dx] = alds[r][px1 + dx];
        }

    // taps with zero (pad) activations, per pixel
    int inv0 = 0, inv1 = 0;
    if (h == 0)   { inv0 |= 0007; inv1 |= 0007; }   // taps 0,1,2 (octal 0b000000111)
    if (h == 127) { inv0 |= 0700; inv1 |= 0700; }   // taps 6,7,8
    if (px0 == 0)   inv0 |= 0111;                   // dx=0 taps 0,3,6
    if (px1 == 127) inv1 |= 0444;                   // dx=2 taps 2,5,8

    long obase = (long)b * 256 * 128 * 128 + (long)h * 128;
    for (int oci = 0; oci < 64; ++oci) {
        int oc = wv * 64 + oci;
        const uint32_t* wp = &wlds[oc * 36];
        int p0a = 0, p0b = 0, p1a = 0, p1b = 0;
#pragma unroll
        for (int t = 0; t < 9; ++t) {
            uint4 wt = *reinterpret_cast<const uint4*>(&wp[t * 4]);
            p0a += __builtin_popcount(a0[t].x ^ wt.x) + __builtin_popcount(a0[t].y ^ wt.y);
            p0b += __builtin_popcount(a0[t].z ^ wt.z) + __builtin_popcount(a0[t].w ^ wt.w);
            p1a += __builtin_popcount(a1[t].x ^ wt.x) + __builtin_popcount(a1[t].y ^ wt.y);
            p1b += __builtin_popcount(a1[t].z ^ wt.z) + __builtin_popcount(a1[t].w ^ wt.w);
        }
        int t0 = 9 * 128 - 2 * (p0a + p0b);
        int t1 = 9 * 128 - 2 * (p1a + p1b);
        if (inv0) {
#pragma unroll
            for (int t = 0; t < 9; ++t)
                if ((inv0 >> t) & 1) t0 -= 128 - 2 * popcW[oc * 9 + t];
        }
        if (inv1) {
#pragma unroll
            for (int t = 0; t < 9; ++t)
                if ((inv1 >> t) & 1) t1 -= 128 - 2 * popcW[oc * 9 + t];
        }
        float s = scaleW[oc], b0v = pb0[oc], al = alpha[oc], b1v = pb1[oc];
        float y0 = s * (float)t0 + b0v;
        y0 = (y0 >= 0.f) ? y0 : al * y0;
        y0 += b1v;
        float y1 = s * (float)t1 + b0v;
        y1 = (y1 >= 0.f) ? y1 : al * y1;
        y1 += b1v;
        long o = obase + (long)oc * 128 * 128;
        out[o + px0] = y0;
        out[o + px1] = y1;
    }
}

// ---------------------------------------------------------------------------
extern "C" void kernel_launch(void* const* d_in, const int* in_sizes, int n_in,
                              void* d_out, int out_size, void* d_ws, size_t ws_size,
                              hipStream_t stream) {
    const float* x          = (const float*)d_in[0];  // (8,128,256,256)
    const float* weight     = (const float*)d_in[1];  // (256,128,3,3)
    const float* move0_bias = (const float*)d_in[2];  // 128
    const float* pb0        = (const float*)d_in[3];  // 256
    const float* alpha      = (const float*)d_in[4];  // 256
    const float* pb1        = (const float*)d_in[5];  // 256
    float* out = (float*)d_out;

    char* ws = (char*)d_ws;
    uint32_t* packedA = (uint32_t*)ws;                        // 2,097,152 B
    uint32_t* packedW = (uint32_t*)(ws + 2097152);            //    36,864 B
    float*    scaleW  = (float*)  (ws + 2097152 + 36864);     //     1,024 B
    int*      popcW   = (int*)    (ws + 2097152 + 36864 + 1024); //  9,216 B

    wprep_kernel<<<256, 128, 0, stream>>>(weight, packedW, scaleW, popcW);
    pool_pack_kernel<<<dim3(128, 8), 256, 0, stream>>>(x, move0_bias, packedA);
    conv_kernel<<<dim3(128, 8), 256, 0, stream>>>(packedA, packedW, scaleW, popcW,
                                                  pb0, alpha, pb1, out);
}